// Round 1
// baseline (399.418 us; speedup 1.0000x reference)
//
#include <hip/hip_runtime.h>
#include <math.h>

#define NB 64
#define NO 32
#define NP 5456
#define NC 80
#define NSLOT 45
#define EPSF 1e-7f

// loss = -(pos ? alpha*(1-p)^2*log_sigmoid(x) : (1-alpha)*p^2*log_sigmoid(-x))
//      =  pos ? 0.25*(1-p)^2*softplus(-x) : 0.75*p^2*softplus(x)
__device__ __forceinline__ float focal_term(float x, bool pos) {
    float ax  = fabsf(x);
    float eax = expf(-ax);
    float l1  = log1pf(eax);
    float sp_x  = fmaxf(x, 0.f) + l1;    // softplus(x)
    float sp_nx = fmaxf(-x, 0.f) + l1;   // softplus(-x)
    float q = 1.f / (1.f + eax);         // sigmoid(|x|)
    float p = (x >= 0.f) ? q : eax * q;  // sigmoid(x)
    float om = 1.f - p;
    return pos ? 0.25f * om * om * sp_nx
               : 0.75f * p  * p  * sp_x;
}

__global__ __launch_bounds__(256) void atss_assign(
    const float4* __restrict__ locs,    // [NB*NP]
    const float4* __restrict__ boxes,   // [NB*NO]
    const int*    __restrict__ labels,  // [NB*NO]
    const float4* __restrict__ priors,  // [NP]
    int*    __restrict__ labs,          // [NB*NP], pre-zeroed
    float4* __restrict__ tb,            // [NB*NSLOT]
    float4* __restrict__ db,            // [NB*NSLOT]
    int*    __restrict__ mk,            // [NB*NSLOT]
    int*    __restrict__ npos)
{
    const int b = blockIdx.x;
    const int tid = threadIdx.x;

    __shared__ float2 s_pr[2048];          // staged prior centers (chunk)
    __shared__ float  s_top_d[256][9];     // per-thread top-9 distances
    __shared__ int    s_top_i[256][9];     // per-thread top-9 level-local idx
    __shared__ int    s_ci[NO][NSLOT];     // candidate GLOBAL prior index
    __shared__ float  s_cp[NO][NSLOT];     // candidate IoU (pov)
    __shared__ float  s_iouc[NO][48];      // masked iou for slot argmax (padded)
    __shared__ float4 s_bx[NO];
    __shared__ float2 s_gtc[NO];
    __shared__ int    s_lab[NO];
    __shared__ int    s_ob[NSLOT], s_match[NSLOT], s_pidx[NSLOT];

    if (tid < NO) {
        float4 bx = boxes[b*NO + tid];
        s_bx[tid]  = bx;
        s_gtc[tid] = make_float2((bx.x + bx.z)*0.5f, (bx.y + bx.w)*0.5f);
        s_lab[tid] = labels[b*NO + tid];
    }
    __syncthreads();

    const int o = tid >> 3, s = tid & 7;   // 32 GTs x 8 scan segments
    const float gx = s_gtc[o].x, gy = s_gtc[o].y;

    const int LSZ[5]  = {4096, 1024, 256, 64, 16};
    const int LOFF[5] = {0, 4096, 5120, 5376, 5440};

    #pragma unroll
    for (int l = 0; l < 5; ++l) {
        const int S = LSZ[l], base = LOFF[l];
        // per-thread top-9, sorted ascending by (d, idx); statically indexed only
        float bd[9]; int bi[9];
        #pragma unroll
        for (int k = 0; k < 9; ++k) { bd[k] = __builtin_inff(); bi[k] = 0x7fffffff; }

        const int nch = (S + 2047) >> 11;
        for (int ch = 0; ch < nch; ++ch) {
            const int cbase = ch << 11;
            const int cs = (S - cbase < 2048) ? (S - cbase) : 2048;
            __syncthreads();
            for (int j = tid; j < cs; j += 256) {
                float4 pv = priors[base + cbase + j];
                s_pr[j] = make_float2(pv.x, pv.y);
            }
            __syncthreads();
            // interleaved scan: thread s takes j = s, s+8, ... (increasing idx,
            // distinct banks across the 8 segments)
            for (int j = s; j < cs; j += 8) {
                float2 pc = s_pr[j];
                float dx = gx - pc.x, dy = gy - pc.y;
                float d = sqrtf(dx*dx + dy*dy);
                if (d < bd[8]) {   // strict: equal-d keeps existing lower idx
                    bd[8] = d; bi[8] = cbase + j;
                    #pragma unroll
                    for (int k = 8; k > 0; --k) {
                        if (bd[k] < bd[k-1]) {
                            float td = bd[k]; bd[k] = bd[k-1]; bd[k-1] = td;
                            int   ti = bi[k]; bi[k] = bi[k-1]; bi[k-1] = ti;
                        }
                    }
                }
            }
        }
        #pragma unroll
        for (int k = 0; k < 9; ++k) { s_top_d[tid][k] = bd[k]; s_top_i[tid][k] = bi[k]; }
        __syncthreads();

        // 8-way merge of sorted lists, lex (d, idx) — exact top_k tie semantics
        if (tid < NO) {
            int head[8] = {0,0,0,0,0,0,0,0};
            float4 a = s_bx[tid];
            float area_a = (a.z - a.x) * (a.w - a.y);
            for (int r = 0; r < 9; ++r) {
                float md = __builtin_inff(); int mi = 0x7fffffff; int mt = 0;
                #pragma unroll
                for (int t = 0; t < 8; ++t) {
                    int h = head[t];
                    if (h < 9) {
                        float d = s_top_d[tid*8 + t][h];
                        int   i = s_top_i[tid*8 + t][h];
                        if (d < md || (d == md && i < mi)) { md = d; mi = i; mt = t; }
                    }
                }
                #pragma unroll
                for (int t = 0; t < 8; ++t) if (t == mt) head[t]++;   // static idx
                // IoU(gt box, prior-as-box)
                float4 pv = priors[base + mi];
                float bx0 = pv.x - pv.z*0.5f, by0 = pv.y - pv.w*0.5f;
                float bx1 = pv.x + pv.z*0.5f, by1 = pv.y + pv.w*0.5f;
                float w  = fmaxf(fminf(a.z, bx1) - fmaxf(a.x, bx0), 0.f);
                float h2 = fmaxf(fminf(a.w, by1) - fmaxf(a.y, by0), 0.f);
                float inter = w * h2;
                float area_b = (bx1 - bx0) * (by1 - by0);
                float iou = inter / (area_a + area_b - inter + EPSF);
                s_ci[tid][l*9 + r] = base + mi;
                s_cp[tid][l*9 + r] = iou;
            }
        }
        __syncthreads();
    }

    // threshold (mean + std ddof=1 over 45) and masked iou
    if (tid < NO) {
        float sum = 0.f;
        for (int k = 0; k < NSLOT; ++k) sum += s_cp[tid][k];
        float mean = sum / 45.f;
        float var = 0.f;
        for (int k = 0; k < NSLOT; ++k) { float d = s_cp[tid][k] - mean; var += d*d; }
        float thr = mean + sqrtf(var / 44.f);
        float4 a = s_bx[tid];
        for (int k = 0; k < NSLOT; ++k) {
            float4 pv = priors[s_ci[tid][k]];
            bool inside = (a.x < pv.x) && (pv.x < a.z) && (a.y < pv.y) && (pv.y < a.w);
            float pov = s_cp[tid][k];
            s_iouc[tid][k] = (pov > thr && inside) ? pov : 0.f;
        }
    }
    __syncthreads();

    // per-slot argmax over GTs (first max), records + tb/db/mk writes
    if (tid < NSLOT) {
        const int slot = tid;
        float bv = s_iouc[0][slot]; int ob = 0;
        for (int oo = 1; oo < NO; ++oo) {
            float v = s_iouc[oo][slot];
            if (v > bv) { bv = v; ob = oo; }
        }
        const int match = (bv > 0.f) ? 1 : 0;
        const int pidx = s_ci[ob][slot];
        s_ob[slot] = ob; s_match[slot] = match; s_pidx[slot] = pidx;
        tb[b*NSLOT + slot] = s_bx[ob];
        mk[b*NSLOT + slot] = match;
        // decode dec[pidx]
        float4 lc = locs[b*NP + pidx];
        float4 pv = priors[pidx];
        float cx = lc.x * pv.z / 10.f + pv.x;
        float cy = lc.y * pv.w / 10.f + pv.y;
        float wd = expf(lc.z / 5.f) * pv.z;
        float hd = expf(lc.w / 5.f) * pv.w;
        db[b*NSLOT + slot] = make_float4(cx - wd*0.5f, cy - hd*0.5f,
                                         cx + wd*0.5f, cy + hd*0.5f);
    }
    __syncthreads();

    // serial label writes in reference (l,c) order + distinct-positive count
    if (tid == 0) {
        int cnt = 0;
        for (int s1 = 0; s1 < NSLOT; ++s1) {
            if (s_match[s1]) {
                labs[b*NP + s_pidx[s1]] = s_lab[s_ob[s1]];
                bool dup = false;
                for (int s2 = 0; s2 < s1; ++s2)
                    if (s_match[s2] && s_pidx[s2] == s_pidx[s1]) dup = true;
                if (!dup) ++cnt;
            }
        }
        if (cnt) atomicAdd(npos, cnt);
    }
}

__global__ __launch_bounds__(256) void focal_kernel(
    const float4* __restrict__ sc4,
    const int*    __restrict__ labs,
    double*       __restrict__ acc,
    int total4)
{
    float lsum = 0.f;
    const int stride = gridDim.x * 256;
    for (int e4 = blockIdx.x * 256 + threadIdx.x; e4 < total4; e4 += stride) {
        const int e  = e4 << 2;
        const int bp = e / NC;        // 80 % 4 == 0 -> float4 stays in one row
        const int c0 = e - bp * NC;
        const int lab = labs[bp];
        const float4 v = sc4[e4];
        lsum += focal_term(v.x, lab == c0 + 1);
        lsum += focal_term(v.y, lab == c0 + 2);
        lsum += focal_term(v.z, lab == c0 + 3);
        lsum += focal_term(v.w, lab == c0 + 4);
    }
    #pragma unroll
    for (int off = 32; off > 0; off >>= 1) lsum += __shfl_down(lsum, off);
    __shared__ float wsum[4];
    const int lane = threadIdx.x & 63, wid = threadIdx.x >> 6;
    if (lane == 0) wsum[wid] = lsum;
    __syncthreads();
    if (threadIdx.x == 0)
        atomicAdd(acc, (double)(wsum[0] + wsum[1] + wsum[2] + wsum[3]));
}

__global__ __launch_bounds__(256) void ciou_kernel(
    const float4* __restrict__ db, const float4* __restrict__ tb,
    const int*    __restrict__ mk,
    double* __restrict__ cacc, int* __restrict__ ccnt, int n)
{
    const int i = blockIdx.x * 256 + threadIdx.x;
    float lsum = 0.f; int lcnt = 0;
    if (i < n && mk[i]) {
        float4 p = db[i], t = tb[i];
        float pw = p.z - p.x, ph = p.w - p.y;
        float tw = t.z - t.x, th = t.w - t.y;
        float iw = fmaxf(fminf(p.z, t.z) - fmaxf(p.x, t.x), 0.f);
        float ih = fmaxf(fminf(p.w, t.w) - fmaxf(p.y, t.y), 0.f);
        float inter = iw * ih;
        float uni = pw*ph + tw*th - inter;
        float iou = inter / (uni + EPSF);
        float cw = fmaxf(p.z, t.z) - fminf(p.x, t.x);
        float ch = fmaxf(p.w, t.w) - fminf(p.y, t.y);
        float c2 = cw*cw + ch*ch + EPSF;
        float ddx = p.x + p.z - t.x - t.z, ddy = p.y + p.w - t.y - t.w;
        float rho2 = (ddx*ddx + ddy*ddy) * 0.25f;
        float dv = atanf(tw / (th + EPSF)) - atanf(pw / (ph + EPSF));
        float v = (float)(4.0 / (M_PI * M_PI)) * dv * dv;
        float al = v / (1.f - iou + v + EPSF);
        lsum = 1.f - iou + rho2 / c2 + al * v;
        lcnt = 1;
    }
    #pragma unroll
    for (int off = 32; off > 0; off >>= 1) {
        lsum += __shfl_down(lsum, off);
        lcnt += __shfl_down(lcnt, off);
    }
    __shared__ float wsum[4]; __shared__ int wcnt[4];
    const int lane = threadIdx.x & 63, wid = threadIdx.x >> 6;
    if (lane == 0) { wsum[wid] = lsum; wcnt[wid] = lcnt; }
    __syncthreads();
    if (threadIdx.x == 0) {
        atomicAdd(cacc, (double)(wsum[0] + wsum[1] + wsum[2] + wsum[3]));
        int c = wcnt[0] + wcnt[1] + wcnt[2] + wcnt[3];
        if (c) atomicAdd(ccnt, c);
    }
}

__global__ void combine_kernel(const double* __restrict__ facc,
                               const int*    __restrict__ npos,
                               const double* __restrict__ cacc,
                               const int*    __restrict__ ccnt,
                               float*        __restrict__ out)
{
    int npv = *npos; if (npv < 1) npv = 1;
    int ncv = *ccnt; if (ncv < 1) ncv = 1;
    out[0] = (float)(facc[0] / (double)npv + cacc[0] / (double)ncv);
}

extern "C" void kernel_launch(void* const* d_in, const int* in_sizes, int n_in,
                              void* d_out, int out_size, void* d_ws, size_t ws_size,
                              hipStream_t stream)
{
    const float* locs   = (const float*)d_in[0];
    const float* scores = (const float*)d_in[1];
    const float* boxes  = (const float*)d_in[2];
    const int*   labels = (const int*)d_in[3];
    const float* priors = (const float*)d_in[4];

    char* ws = (char*)d_ws;
    double* facc = (double*)(ws + 0);
    double* cacc = (double*)(ws + 8);
    int*    npos = (int*)(ws + 16);
    int*    ccnt = (int*)(ws + 20);
    int*    labs = (int*)(ws + 32);
    size_t off = 32 + (size_t)NB * NP * 4;            // 1,396,768 (16B aligned)
    float4* tb = (float4*)(ws + off); off += (size_t)NB * NSLOT * 16;
    float4* db = (float4*)(ws + off); off += (size_t)NB * NSLOT * 16;
    int*    mk = (int*)(ws + off);

    // zero accumulators + labs (tb/db/mk are fully written each call)
    hipMemsetAsync(d_ws, 0, 32 + (size_t)NB * NP * 4, stream);

    atss_assign<<<NB, 256, 0, stream>>>(
        (const float4*)locs, (const float4*)boxes, labels,
        (const float4*)priors, labs, tb, db, mk, npos);

    const int total4 = NB * NP * NC / 4;
    focal_kernel<<<2048, 256, 0, stream>>>((const float4*)scores, labs, facc, total4);

    ciou_kernel<<<(NB * NSLOT + 255) / 256, 256, 0, stream>>>(db, tb, mk, cacc, ccnt, NB * NSLOT);

    combine_kernel<<<1, 1, 0, stream>>>(facc, npos, cacc, ccnt, (float*)d_out);
}

// Round 2
// 104.187 us; speedup vs baseline: 3.8337x; 3.8337x over previous
//
#include <hip/hip_runtime.h>
#include <math.h>

#define NB 64
#define NO 32
#define NP 5456
#define NC 80
#define NSLOT 45
#define EPSF 1e-7f
#define INF __builtin_inff()

// ---------- focal pieces ----------
// negative term: 0.75 * sigmoid(x)^2 * softplus(x)
__device__ __forceinline__ float focal_neg(float x) {
    float ax  = fabsf(x);
    float eax = __expf(-ax);
    float l1  = __logf(1.f + eax);
    float sp  = fmaxf(x, 0.f) + l1;          // softplus(x)
    float q   = __builtin_amdgcn_rcpf(1.f + eax);
    float p   = (x >= 0.f) ? q : eax * q;    // sigmoid(x)
    return 0.75f * p * p * sp;
}
// positive term: 0.25 * (1-p)^2 * softplus(-x)
__device__ __forceinline__ float focal_pos(float x) {
    float ax  = fabsf(x);
    float eax = __expf(-ax);
    float l1  = __logf(1.f + eax);
    float spn = fmaxf(-x, 0.f) + l1;         // softplus(-x)
    float q   = __builtin_amdgcn_rcpf(1.f + eax);
    float p   = (x >= 0.f) ? q : eax * q;
    float om  = 1.f - p;
    return 0.25f * om * om * spn;
}

// ---------- 1) top-9 per (b, o, level): one wave per task ----------
// task = l*2048 + (b*NO + o); grid = 2560 blocks x 256 (4 waves)
__global__ __launch_bounds__(256) void topk_kernel(
    const float4* __restrict__ boxes,    // [NB*NO]
    const float4* __restrict__ priors,   // [NP]
    int*   __restrict__ ci,              // [NB*NO*NSLOT] global prior idx
    float* __restrict__ cp)              // [NB*NO*NSLOT] candidate IoU
{
    const int lane = threadIdx.x & 63;
    const int task = blockIdx.x * 4 + (threadIdx.x >> 6);
    const int l    = task >> 11;         // 0..4 (uniform per block)
    const int bo   = task & 2047;        // b*NO + o

    const int S    = (l==0)?4096:(l==1)?1024:(l==2)?256:(l==3)?64:16;
    const int base = (l==0)?0:(l==1)?4096:(l==2)?5120:(l==3)?5376:5440;

    const float4 a = boxes[bo];
    const float gx = (a.x + a.z) * 0.5f, gy = (a.y + a.w) * 0.5f;

    // per-lane sorted top-9 (ascending (d, idx)); statically indexed only
    float bd[9]; int bi[9];
    #pragma unroll
    for (int k = 0; k < 9; ++k) { bd[k] = INF; bi[k] = 0x7fffffff; }

    for (int j = lane; j < S; j += 64) {
        float4 pv = priors[base + j];
        float dx = gx - pv.x, dy = gy - pv.y;
        float d = sqrtf(dx * dx + dy * dy);
        if (d < bd[8]) {                 // strict: ties keep lower idx (scan ascending)
            bd[8] = d; bi[8] = j;
            #pragma unroll
            for (int k = 8; k > 0; --k) {
                if (bd[k] < bd[k-1]) {
                    float td = bd[k]; bd[k] = bd[k-1]; bd[k-1] = td;
                    int   ti = bi[k]; bi[k] = bi[k-1]; bi[k-1] = ti;
                }
            }
        }
    }

    // 9 rounds of 64-lane lex-min butterfly; idx unique per lane -> unique owner
    int win = 0;
    #pragma unroll
    for (int r = 0; r < 9; ++r) {
        float d = bd[0]; int i = bi[0];
        #pragma unroll
        for (int off = 1; off < 64; off <<= 1) {
            float od = __shfl_xor(d, off);
            int   oi = __shfl_xor(i, off);
            if (od < d || (od == d && oi < i)) { d = od; i = oi; }
        }
        if (bi[0] == i) {                // owner: pop head (static shift)
            #pragma unroll
            for (int k = 0; k < 8; ++k) { bd[k] = bd[k+1]; bi[k] = bi[k+1]; }
            bd[8] = INF; bi[8] = 0x7fffffff;
        }
        if (lane == r) win = i;
    }

    if (lane < 9) {
        float4 pv = priors[base + win];
        float bx0 = pv.x - pv.z * 0.5f, by0 = pv.y - pv.w * 0.5f;
        float bx1 = pv.x + pv.z * 0.5f, by1 = pv.y + pv.w * 0.5f;
        float w = fmaxf(fminf(a.z, bx1) - fmaxf(a.x, bx0), 0.f);
        float h = fmaxf(fminf(a.w, by1) - fmaxf(a.y, by0), 0.f);
        float inter  = w * h;
        float area_a = (a.z - a.x) * (a.w - a.y);
        float area_b = (bx1 - bx0) * (by1 - by0);
        float iou = inter / (area_a + area_b - inter + EPSF);
        int idx = bo * NSLOT + l * 9 + lane;
        ci[idx] = base + win;
        cp[idx] = iou;
    }
}

// ---------- 2) threshold + argmax + decode + labels + focal pos-correction ----------
__global__ __launch_bounds__(64) void finish_kernel(
    const float4* __restrict__ locs,     // [NB*NP]
    const float4* __restrict__ boxes,    // [NB*NO]
    const int*    __restrict__ labels,   // [NB*NO]
    const float4* __restrict__ priors,   // [NP]
    const float*  __restrict__ scores,   // [NB*NP*NC]
    const int*    __restrict__ ci,
    const float*  __restrict__ cp,
    float4* __restrict__ tb,             // [NB*NSLOT]
    float4* __restrict__ db,             // [NB*NSLOT]
    int*    __restrict__ mk,             // [NB*NSLOT]
    int*    __restrict__ npos,
    double* __restrict__ facc)
{
    const int b = blockIdx.x;
    const int t = threadIdx.x;

    __shared__ int   s_ci[NO * NSLOT];
    __shared__ float s_io[NO * NSLOT];
    __shared__ int   s_pidx[NSLOT], s_ob[NSLOT], s_match[NSLOT];

    // stage candidates (1440 elems = 360 x int4/float4, 16B-aligned)
    const int4*   gci = (const int4*)(ci + b * NO * NSLOT);
    const float4* gcp = (const float4*)(cp + b * NO * NSLOT);
    int4*   sci4 = (int4*)s_ci;
    float4* sio4 = (float4*)s_io;
    for (int k = t; k < NO * NSLOT / 4; k += 64) { sci4[k] = gci[k]; sio4[k] = gcp[k]; }
    __syncthreads();

    // per-GT threshold (mean + std ddof=1 over 45) and masked iou (in place)
    if (t < NO) {
        float sum = 0.f;
        #pragma unroll
        for (int k = 0; k < NSLOT; ++k) sum += s_io[t * NSLOT + k];
        float mean = sum / 45.f;
        float var = 0.f;
        #pragma unroll
        for (int k = 0; k < NSLOT; ++k) { float d = s_io[t * NSLOT + k] - mean; var += d * d; }
        float thr = mean + sqrtf(var / 44.f);
        float4 a = boxes[b * NO + t];
        for (int k = 0; k < NSLOT; ++k) {
            float4 pv = priors[s_ci[t * NSLOT + k]];
            bool inside = (a.x < pv.x) && (pv.x < a.z) && (a.y < pv.y) && (pv.y < a.w);
            float pov = s_io[t * NSLOT + k];
            s_io[t * NSLOT + k] = (pov > thr && inside) ? pov : 0.f;
        }
    }
    __syncthreads();

    // per-slot argmax over GTs (first max), decode, tb/db/mk writes
    if (t < NSLOT) {
        float bv = s_io[t]; int ob = 0;
        for (int oo = 1; oo < NO; ++oo) {
            float v = s_io[oo * NSLOT + t];
            if (v > bv) { bv = v; ob = oo; }
        }
        int match = bv > 0.f;
        int pidx = s_ci[ob * NSLOT + t];
        s_pidx[t] = pidx; s_ob[t] = ob; s_match[t] = match;
        tb[b * NSLOT + t] = boxes[b * NO + ob];
        mk[b * NSLOT + t] = match;
        float4 lc = locs[b * NP + pidx];
        float4 pv = priors[pidx];
        float cx = lc.x * pv.z / 10.f + pv.x;
        float cy = lc.y * pv.w / 10.f + pv.y;
        float wd = expf(lc.z / 5.f) * pv.z;
        float hd = expf(lc.w / 5.f) * pv.w;
        db[b * NSLOT + t] = make_float4(cx - wd * 0.5f, cy - hd * 0.5f,
                                        cx + wd * 0.5f, cy + hd * 0.5f);
    }
    __syncthreads();

    // last-writer-wins label resolution; focal positive correction; distinct count
    int firstocc = 0;
    if (t < NSLOT && s_match[t]) {
        bool last = true, first = true;
        for (int s2 = t + 1; s2 < NSLOT; ++s2)
            if (s_match[s2] && s_pidx[s2] == s_pidx[t]) last = false;
        for (int s2 = 0; s2 < t; ++s2)
            if (s_match[s2] && s_pidx[s2] == s_pidx[t]) first = false;
        if (last) {
            int lab = labels[b * NO + s_ob[t]];           // final label for this prior
            float x = scores[((size_t)b * NP + s_pidx[t]) * NC + (lab - 1)];
            atomicAdd(facc, (double)(focal_pos(x) - focal_neg(x)));
        }
        firstocc = first;
    }
    unsigned long long ball = __ballot(firstocc);
    if (t == 0 && ball) atomicAdd(npos, (int)__popcll(ball));
}

// ---------- 3) all-negative focal over every logit (no labels needed) ----------
__global__ __launch_bounds__(256) void focal_kernel(
    const float4* __restrict__ sc4, double* __restrict__ acc, int total4)
{
    float lsum = 0.f;
    const int stride = gridDim.x * 256;
    for (int e4 = blockIdx.x * 256 + threadIdx.x; e4 < total4; e4 += stride) {
        const float4 v = sc4[e4];
        lsum += focal_neg(v.x);
        lsum += focal_neg(v.y);
        lsum += focal_neg(v.z);
        lsum += focal_neg(v.w);
    }
    #pragma unroll
    for (int off = 32; off > 0; off >>= 1) lsum += __shfl_down(lsum, off);
    __shared__ float wsum[4];
    const int lane = threadIdx.x & 63, wid = threadIdx.x >> 6;
    if (lane == 0) wsum[wid] = lsum;
    __syncthreads();
    if (threadIdx.x == 0)
        atomicAdd(acc, (double)(wsum[0] + wsum[1] + wsum[2] + wsum[3]));
}

// ---------- 4) ciou + final combine (single block) ----------
__global__ __launch_bounds__(256) void ciou_combine(
    const float4* __restrict__ db, const float4* __restrict__ tb,
    const int* __restrict__ mk,
    const double* __restrict__ facc, const int* __restrict__ npos,
    float* __restrict__ out)
{
    float lsum = 0.f, lcnt = 0.f;
    for (int i = threadIdx.x; i < NB * NSLOT; i += 256) {
        if (mk[i]) {
            float4 p = db[i], t4 = tb[i];
            float pw = p.z - p.x, ph = p.w - p.y;
            float tw = t4.z - t4.x, th = t4.w - t4.y;
            float iw = fmaxf(fminf(p.z, t4.z) - fmaxf(p.x, t4.x), 0.f);
            float ih = fmaxf(fminf(p.w, t4.w) - fmaxf(p.y, t4.y), 0.f);
            float inter = iw * ih;
            float uni = pw * ph + tw * th - inter;
            float iou = inter / (uni + EPSF);
            float cw = fmaxf(p.z, t4.z) - fminf(p.x, t4.x);
            float ch = fmaxf(p.w, t4.w) - fminf(p.y, t4.y);
            float c2 = cw * cw + ch * ch + EPSF;
            float ddx = p.x + p.z - t4.x - t4.z, ddy = p.y + p.w - t4.y - t4.w;
            float rho2 = (ddx * ddx + ddy * ddy) * 0.25f;
            float dv = atanf(tw / (th + EPSF)) - atanf(pw / (ph + EPSF));
            float v = (float)(4.0 / (M_PI * M_PI)) * dv * dv;
            float al = v / (1.f - iou + v + EPSF);
            lsum += 1.f - iou + rho2 / c2 + al * v;
            lcnt += 1.f;
        }
    }
    #pragma unroll
    for (int off = 32; off > 0; off >>= 1) {
        lsum += __shfl_down(lsum, off);
        lcnt += __shfl_down(lcnt, off);
    }
    __shared__ float ws[4], wc[4];
    const int lane = threadIdx.x & 63, wid = threadIdx.x >> 6;
    if (lane == 0) { ws[wid] = lsum; wc[wid] = lcnt; }
    __syncthreads();
    if (threadIdx.x == 0) {
        float sum = ws[0] + ws[1] + ws[2] + ws[3];
        float cnt = wc[0] + wc[1] + wc[2] + wc[3];
        int npv = *npos; if (npv < 1) npv = 1;
        out[0] = (float)(facc[0] / (double)npv) + sum / fmaxf(cnt, 1.f);
    }
}

extern "C" void kernel_launch(void* const* d_in, const int* in_sizes, int n_in,
                              void* d_out, int out_size, void* d_ws, size_t ws_size,
                              hipStream_t stream)
{
    const float* locs   = (const float*)d_in[0];
    const float* scores = (const float*)d_in[1];
    const float* boxes  = (const float*)d_in[2];
    const int*   labels = (const int*)d_in[3];
    const float* priors = (const float*)d_in[4];

    char* ws = (char*)d_ws;
    double* facc = (double*)(ws + 0);
    int*    npos = (int*)(ws + 8);
    int*    ci   = (int*)(ws + 16);                       // NB*NO*45 ints
    size_t off = 16 + (size_t)NB * NO * NSLOT * 4;        // 368,656
    float*  cp = (float*)(ws + off); off += (size_t)NB * NO * NSLOT * 4;
    float4* tb = (float4*)(ws + off); off += (size_t)NB * NSLOT * 16;
    float4* db = (float4*)(ws + off); off += (size_t)NB * NSLOT * 16;
    int*    mk = (int*)(ws + off);

    hipMemsetAsync(d_ws, 0, 16, stream);                  // facc + npos only

    topk_kernel<<<2560, 256, 0, stream>>>(
        (const float4*)boxes, (const float4*)priors, ci, cp);

    finish_kernel<<<NB, 64, 0, stream>>>(
        (const float4*)locs, (const float4*)boxes, labels,
        (const float4*)priors, scores, ci, cp, tb, db, mk, npos, facc);

    const int total4 = NB * NP * NC / 4;
    focal_kernel<<<2048, 256, 0, stream>>>((const float4*)scores, facc, total4);

    ciou_combine<<<1, 256, 0, stream>>>(db, tb, mk, facc, npos, (float*)d_out);
}

// Round 3
// 98.174 us; speedup vs baseline: 4.0685x; 1.0612x over previous
//
#include <hip/hip_runtime.h>
#include <math.h>

#define NB 64
#define NO 32
#define NP 5456
#define NC 80
#define NSLOT 45
#define EPSF 1e-7f
#define INF __builtin_inff()

// ---------- focal pieces ----------
// negative term: 0.75 * sigmoid(x)^2 * softplus(x)
__device__ __forceinline__ float focal_neg(float x) {
    float ax  = fabsf(x);
    float eax = __expf(-ax);
    float l1  = __logf(1.f + eax);
    float sp  = fmaxf(x, 0.f) + l1;          // softplus(x)
    float q   = __builtin_amdgcn_rcpf(1.f + eax);
    float p   = (x >= 0.f) ? q : eax * q;    // sigmoid(x)
    return 0.75f * p * p * sp;
}
// positive term: 0.25 * (1-p)^2 * softplus(-x)
__device__ __forceinline__ float focal_pos(float x) {
    float ax  = fabsf(x);
    float eax = __expf(-ax);
    float l1  = __logf(1.f + eax);
    float spn = fmaxf(-x, 0.f) + l1;         // softplus(-x)
    float q   = __builtin_amdgcn_rcpf(1.f + eax);
    float p   = (x >= 0.f) ? q : eax * q;
    float om  = 1.f - p;
    return 0.25f * om * om * spn;
}

// ---------- 1) top-9 per (b, o, level): one wave per task ----------
// task = l*2048 + (b*NO + o); grid = 2560 blocks x 256 (4 waves)
// Also zeroes the accumulators (block 0) — replaces the hipMemsetAsync node.
__global__ __launch_bounds__(256) void topk_kernel(
    const float4* __restrict__ boxes,    // [NB*NO]
    const float4* __restrict__ priors,   // [NP]
    int*   __restrict__ ci,              // [NB*NO*NSLOT] global prior idx
    float* __restrict__ cp,              // [NB*NO*NSLOT] candidate IoU
    double* __restrict__ facc,
    int*    __restrict__ npos)
{
    if (blockIdx.x == 0 && threadIdx.x == 0) { *facc = 0.0; *npos = 0; }

    const int lane = threadIdx.x & 63;
    const int task = blockIdx.x * 4 + (threadIdx.x >> 6);
    const int l    = task >> 11;         // 0..4 (uniform per block)
    const int bo   = task & 2047;        // b*NO + o

    const int S    = (l==0)?4096:(l==1)?1024:(l==2)?256:(l==3)?64:16;
    const int base = (l==0)?0:(l==1)?4096:(l==2)?5120:(l==3)?5376:5440;

    const float4 a = boxes[bo];
    const float gx = (a.x + a.z) * 0.5f, gy = (a.y + a.w) * 0.5f;

    // per-lane sorted top-9 (ascending (d, idx)); statically indexed only
    float bd[9]; int bi[9];
    #pragma unroll
    for (int k = 0; k < 9; ++k) { bd[k] = INF; bi[k] = 0x7fffffff; }

    for (int j = lane; j < S; j += 64) {
        float4 pv = priors[base + j];
        float dx = gx - pv.x, dy = gy - pv.y;
        float d = sqrtf(dx * dx + dy * dy);
        if (d < bd[8]) {                 // strict: ties keep lower idx (scan ascending)
            bd[8] = d; bi[8] = j;
            #pragma unroll
            for (int k = 8; k > 0; --k) {
                if (bd[k] < bd[k-1]) {
                    float td = bd[k]; bd[k] = bd[k-1]; bd[k-1] = td;
                    int   ti = bi[k]; bi[k] = bi[k-1]; bi[k-1] = ti;
                }
            }
        }
    }

    // 9 rounds of 64-lane lex-min butterfly; idx unique per lane -> unique owner
    int win = 0;
    #pragma unroll
    for (int r = 0; r < 9; ++r) {
        float d = bd[0]; int i = bi[0];
        #pragma unroll
        for (int off = 1; off < 64; off <<= 1) {
            float od = __shfl_xor(d, off);
            int   oi = __shfl_xor(i, off);
            if (od < d || (od == d && oi < i)) { d = od; i = oi; }
        }
        if (bi[0] == i) {                // owner: pop head (static shift)
            #pragma unroll
            for (int k = 0; k < 8; ++k) { bd[k] = bd[k+1]; bi[k] = bi[k+1]; }
            bd[8] = INF; bi[8] = 0x7fffffff;
        }
        if (lane == r) win = i;
    }

    if (lane < 9) {
        float4 pv = priors[base + win];
        float bx0 = pv.x - pv.z * 0.5f, by0 = pv.y - pv.w * 0.5f;
        float bx1 = pv.x + pv.z * 0.5f, by1 = pv.y + pv.w * 0.5f;
        float w = fmaxf(fminf(a.z, bx1) - fmaxf(a.x, bx0), 0.f);
        float h = fmaxf(fminf(a.w, by1) - fmaxf(a.y, by0), 0.f);
        float inter  = w * h;
        float area_a = (a.z - a.x) * (a.w - a.y);
        float area_b = (bx1 - bx0) * (by1 - by0);
        float iou = inter / (area_a + area_b - inter + EPSF);
        int idx = bo * NSLOT + l * 9 + lane;
        ci[idx] = base + win;
        cp[idx] = iou;
    }
}

// ---------- 2) threshold + argmax + decode + labels + focal pos-correction ----------
__global__ __launch_bounds__(64) void finish_kernel(
    const float4* __restrict__ locs,     // [NB*NP]
    const float4* __restrict__ boxes,    // [NB*NO]
    const int*    __restrict__ labels,   // [NB*NO]
    const float4* __restrict__ priors,   // [NP]
    const float*  __restrict__ scores,   // [NB*NP*NC]
    const int*    __restrict__ ci,
    const float*  __restrict__ cp,
    float4* __restrict__ tb,             // [NB*NSLOT]
    float4* __restrict__ db,             // [NB*NSLOT]
    int*    __restrict__ mk,             // [NB*NSLOT]
    int*    __restrict__ npos,
    double* __restrict__ facc)
{
    const int b = blockIdx.x;
    const int t = threadIdx.x;

    __shared__ int   s_ci[NO * NSLOT];
    __shared__ float s_io[NO * NSLOT];
    __shared__ int   s_pidx[NSLOT], s_ob[NSLOT], s_match[NSLOT];

    // stage candidates (1440 elems = 360 x int4/float4, 16B-aligned)
    const int4*   gci = (const int4*)(ci + b * NO * NSLOT);
    const float4* gcp = (const float4*)(cp + b * NO * NSLOT);
    int4*   sci4 = (int4*)s_ci;
    float4* sio4 = (float4*)s_io;
    for (int k = t; k < NO * NSLOT / 4; k += 64) { sci4[k] = gci[k]; sio4[k] = gcp[k]; }
    __syncthreads();

    // per-GT threshold (mean + std ddof=1 over 45) and masked iou (in place)
    if (t < NO) {
        float sum = 0.f;
        #pragma unroll
        for (int k = 0; k < NSLOT; ++k) sum += s_io[t * NSLOT + k];
        float mean = sum / 45.f;
        float var = 0.f;
        #pragma unroll
        for (int k = 0; k < NSLOT; ++k) { float d = s_io[t * NSLOT + k] - mean; var += d * d; }
        float thr = mean + sqrtf(var / 44.f);
        float4 a = boxes[b * NO + t];
        for (int k = 0; k < NSLOT; ++k) {
            float4 pv = priors[s_ci[t * NSLOT + k]];
            bool inside = (a.x < pv.x) && (pv.x < a.z) && (a.y < pv.y) && (pv.y < a.w);
            float pov = s_io[t * NSLOT + k];
            s_io[t * NSLOT + k] = (pov > thr && inside) ? pov : 0.f;
        }
    }
    __syncthreads();

    // per-slot argmax over GTs (first max), decode, tb/db/mk writes
    if (t < NSLOT) {
        float bv = s_io[t]; int ob = 0;
        for (int oo = 1; oo < NO; ++oo) {
            float v = s_io[oo * NSLOT + t];
            if (v > bv) { bv = v; ob = oo; }
        }
        int match = bv > 0.f;
        int pidx = s_ci[ob * NSLOT + t];
        s_pidx[t] = pidx; s_ob[t] = ob; s_match[t] = match;
        tb[b * NSLOT + t] = boxes[b * NO + ob];
        mk[b * NSLOT + t] = match;
        float4 lc = locs[b * NP + pidx];
        float4 pv = priors[pidx];
        float cx = lc.x * pv.z / 10.f + pv.x;
        float cy = lc.y * pv.w / 10.f + pv.y;
        float wd = expf(lc.z / 5.f) * pv.z;
        float hd = expf(lc.w / 5.f) * pv.w;
        db[b * NSLOT + t] = make_float4(cx - wd * 0.5f, cy - hd * 0.5f,
                                        cx + wd * 0.5f, cy + hd * 0.5f);
    }
    __syncthreads();

    // last-writer-wins label resolution; focal positive correction; distinct count
    int firstocc = 0;
    if (t < NSLOT && s_match[t]) {
        bool last = true, first = true;
        for (int s2 = t + 1; s2 < NSLOT; ++s2)
            if (s_match[s2] && s_pidx[s2] == s_pidx[t]) last = false;
        for (int s2 = 0; s2 < t; ++s2)
            if (s_match[s2] && s_pidx[s2] == s_pidx[t]) first = false;
        if (last) {
            int lab = labels[b * NO + s_ob[t]];           // final label for this prior
            float x = scores[((size_t)b * NP + s_pidx[t]) * NC + (lab - 1)];
            atomicAdd(facc, (double)(focal_pos(x) - focal_neg(x)));
        }
        firstocc = first;
    }
    unsigned long long ball = __ballot(firstocc);
    if (t == 0 && ball) atomicAdd(npos, (int)__popcll(ball));
}

// ---------- 3) all-negative focal over every logit (no labels needed) ----------
__global__ __launch_bounds__(256) void focal_kernel(
    const float4* __restrict__ sc4, double* __restrict__ acc, int total4)
{
    float lsum = 0.f;
    const int stride = gridDim.x * 256;
    for (int e4 = blockIdx.x * 256 + threadIdx.x; e4 < total4; e4 += stride) {
        const float4 v = sc4[e4];
        lsum += focal_neg(v.x);
        lsum += focal_neg(v.y);
        lsum += focal_neg(v.z);
        lsum += focal_neg(v.w);
    }
    #pragma unroll
    for (int off = 32; off > 0; off >>= 1) lsum += __shfl_down(lsum, off);
    __shared__ float wsum[4];
    const int lane = threadIdx.x & 63, wid = threadIdx.x >> 6;
    if (lane == 0) wsum[wid] = lsum;
    __syncthreads();
    if (threadIdx.x == 0)
        atomicAdd(acc, (double)(wsum[0] + wsum[1] + wsum[2] + wsum[3]));
}

// ---------- 4) ciou + final combine (single block) ----------
__global__ __launch_bounds__(256) void ciou_combine(
    const float4* __restrict__ db, const float4* __restrict__ tb,
    const int* __restrict__ mk,
    const double* __restrict__ facc, const int* __restrict__ npos,
    float* __restrict__ out)
{
    float lsum = 0.f, lcnt = 0.f;
    for (int i = threadIdx.x; i < NB * NSLOT; i += 256) {
        if (mk[i]) {
            float4 p = db[i], t4 = tb[i];
            float pw = p.z - p.x, ph = p.w - p.y;
            float tw = t4.z - t4.x, th = t4.w - t4.y;
            float iw = fmaxf(fminf(p.z, t4.z) - fmaxf(p.x, t4.x), 0.f);
            float ih = fmaxf(fminf(p.w, t4.w) - fmaxf(p.y, t4.y), 0.f);
            float inter = iw * ih;
            float uni = pw * ph + tw * th - inter;
            float iou = inter / (uni + EPSF);
            float cw = fmaxf(p.z, t4.z) - fminf(p.x, t4.x);
            float ch = fmaxf(p.w, t4.w) - fminf(p.y, t4.y);
            float c2 = cw * cw + ch * ch + EPSF;
            float ddx = p.x + p.z - t4.x - t4.z, ddy = p.y + p.w - t4.y - t4.w;
            float rho2 = (ddx * ddx + ddy * ddy) * 0.25f;
            float dv = atanf(tw / (th + EPSF)) - atanf(pw / (ph + EPSF));
            float v = (float)(4.0 / (M_PI * M_PI)) * dv * dv;
            float al = v / (1.f - iou + v + EPSF);
            lsum += 1.f - iou + rho2 / c2 + al * v;
            lcnt += 1.f;
        }
    }
    #pragma unroll
    for (int off = 32; off > 0; off >>= 1) {
        lsum += __shfl_down(lsum, off);
        lcnt += __shfl_down(lcnt, off);
    }
    __shared__ float ws[4], wc[4];
    const int lane = threadIdx.x & 63, wid = threadIdx.x >> 6;
    if (lane == 0) { ws[wid] = lsum; wc[wid] = lcnt; }
    __syncthreads();
    if (threadIdx.x == 0) {
        float sum = ws[0] + ws[1] + ws[2] + ws[3];
        float cnt = wc[0] + wc[1] + wc[2] + wc[3];
        int npv = *npos; if (npv < 1) npv = 1;
        out[0] = (float)(facc[0] / (double)npv) + sum / fmaxf(cnt, 1.f);
    }
}

extern "C" void kernel_launch(void* const* d_in, const int* in_sizes, int n_in,
                              void* d_out, int out_size, void* d_ws, size_t ws_size,
                              hipStream_t stream)
{
    const float* locs   = (const float*)d_in[0];
    const float* scores = (const float*)d_in[1];
    const float* boxes  = (const float*)d_in[2];
    const int*   labels = (const int*)d_in[3];
    const float* priors = (const float*)d_in[4];

    char* ws = (char*)d_ws;
    double* facc = (double*)(ws + 0);
    int*    npos = (int*)(ws + 8);
    int*    ci   = (int*)(ws + 16);                       // NB*NO*45 ints
    size_t off = 16 + (size_t)NB * NO * NSLOT * 4;        // 368,656
    float*  cp = (float*)(ws + off); off += (size_t)NB * NO * NSLOT * 4;
    float4* tb = (float4*)(ws + off); off += (size_t)NB * NSLOT * 16;
    float4* db = (float4*)(ws + off); off += (size_t)NB * NSLOT * 16;
    int*    mk = (int*)(ws + off);

    // no memset node: topk_kernel block 0 zeroes facc/npos; everything else
    // (ci/cp/tb/db/mk/out) is fully rewritten every call.

    topk_kernel<<<2560, 256, 0, stream>>>(
        (const float4*)boxes, (const float4*)priors, ci, cp, facc, npos);

    finish_kernel<<<NB, 64, 0, stream>>>(
        (const float4*)locs, (const float4*)boxes, labels,
        (const float4*)priors, scores, ci, cp, tb, db, mk, npos, facc);

    const int total4 = NB * NP * NC / 4;
    focal_kernel<<<2048, 256, 0, stream>>>((const float4*)scores, facc, total4);

    ciou_combine<<<1, 256, 0, stream>>>(db, tb, mk, facc, npos, (float*)d_out);
}